// Round 15
// baseline (75.685 us; speedup 1.0000x reference)
//
#include <hip/hip_runtime.h>

// Periodogram: out[b,m] = (re^2 + im^2)/N,  re = aC + bS, im = bC - aS
// r15: r14's barrier-free streaming + register ping-pong PREFETCH of the
// next K-step's A/B fragments (loads for t+1 issue before t's MFMAs, so
// L2 latency hides under compute). No LDS, no K-loop barriers.

typedef __fp16 half8  __attribute__((ext_vector_type(8)));
typedef __fp16 half2v __attribute__((ext_vector_type(2)));
typedef float  f32x4  __attribute__((ext_vector_type(4)));

#define B_SZ 512
#define N_SZ 1024
#define M_SZ 16384
#define BT 128
#define MT 128
#define KT 32
#define WS_ARR 1048576   // bytes per converted array (512*1024*2)

union U4 { half2v h2[4]; uint4 u; };
union BF { half2v h2[4]; half8 v; uint4 u; };

// ---- pre-kernel: x (f32) -> d_ws (f16, fragment-tiled) ----
__global__ __launch_bounds__(256)
void cvt_kernel(const float* __restrict__ x, unsigned char* __restrict__ ws) {
    const int id  = (int)blockIdx.x * 256 + (int)threadIdx.x;  // 0..131071
    const int arr = id >> 16;            // 0=a, 1=b
    const int rem = id & 65535;
    const int rb  = rem >> 11;           // row block 0..31
    const int kc  = (rem >> 6) & 31;     // k chunk 0..31
    const int l6  = rem & 63;
    const int r16 = l6 >> 2;             // row in block
    const int g   = l6 & 3;              // k sub-group
    const float* src = x + (size_t)(rb * 16 + r16) * 2048 + arr * 1024 + kc * 32 + g * 8;
    const float4 v0 = *(const float4*)src;
    const float4 v1 = *(const float4*)(src + 4);
    U4 u;
    u.h2[0] = __builtin_amdgcn_cvt_pkrtz(v0.x, v0.y);
    u.h2[1] = __builtin_amdgcn_cvt_pkrtz(v0.z, v0.w);
    u.h2[2] = __builtin_amdgcn_cvt_pkrtz(v1.x, v1.y);
    u.h2[3] = __builtin_amdgcn_cvt_pkrtz(v1.z, v1.w);
    *(uint4*)(ws + (size_t)arr * WS_ARR + (size_t)(rb * 32 + kc) * 1024 + (g * 16 + r16) * 16) = u.u;
}

__global__ __launch_bounds__(256, 2)
void periodogram_kernel(const unsigned char* __restrict__ ws,
                        const float* __restrict__ xgrid,
                        float* __restrict__ out) {
    const int tid  = (int)threadIdx.x;
    const int lane = tid & 63;
    const int w    = tid >> 6;
    const int bid  = (int)blockIdx.x;
    const int b0 = (bid & 3) * BT;
    const int m0 = (bid >> 2) * MT;

    const int wr = (w >> 1) * 64;   // wave row offset in tile
    const int wc = (w & 1) * 64;    // wave col offset in tile

    // ---- fragment source pointers (lane-linear within 1KB tiles) ----
    const unsigned char* pA[4];
    const unsigned char* pB[4];
#pragma unroll
    for (int fm = 0; fm < 4; ++fm) {
        const int rb = ((b0 + wr) >> 4) + fm;
        pA[fm] = ws + (size_t)(rb * 32) * 1024 + (size_t)(lane * 16);
        pB[fm] = pA[fm] + WS_ARR;
    }

    // ---- per-lane trig state for the B operand (register-resident) ----
    half2v PC[4][4], PS[4][4];
    float c0v[4], s0v[4], C32[4], S32[4];
    const float g8f = (float)((lane >> 4) << 3);
#pragma unroll
    for (int fn = 0; fn < 4; ++fn) {
        const float xg = xgrid[m0 + wc + fn * 16 + (lane & 15)];
        float Cj[8], Sj[8];
        Cj[0] = 1.0f; Sj[0] = 0.0f;
#pragma unroll
        for (int j = 1; j < 8; ++j) {
            float p = xg * (float)j; p -= floorf(p);
            Cj[j] = __builtin_amdgcn_cosf(p);   // cos(2*pi*p)
            Sj[j] = __builtin_amdgcn_sinf(p);
        }
#pragma unroll
        for (int i = 0; i < 4; ++i) {
            PC[fn][i] = __builtin_amdgcn_cvt_pkrtz(Cj[2 * i], Cj[2 * i + 1]);
            PS[fn][i] = __builtin_amdgcn_cvt_pkrtz(Sj[2 * i], Sj[2 * i + 1]);
        }
        float p32 = xg * 32.0f; p32 -= floorf(p32);      // exact product
        C32[fn] = __builtin_amdgcn_cosf(p32);
        S32[fn] = __builtin_amdgcn_sinf(p32);
        float pb = xg * g8f; pb -= floorf(pb);
        c0v[fn] = __builtin_amdgcn_cosf(pb);
        s0v[fn] = __builtin_amdgcn_sinf(pb);
    }

    f32x4 accRe[4][4], accIm[4][4];
#pragma unroll
    for (int i = 0; i < 4; ++i)
#pragma unroll
        for (int j = 0; j < 4; ++j) { accRe[i][j] = (f32x4)0.0f; accIm[i][j] = (f32x4)0.0f; }

    half8 A0[4], B0[4], A1[4], B1[4];

#define LOADF(FA, FB, T)                                                      \
    do {                                                                      \
        const unsigned _o = (unsigned)((T) * 1024);                           \
        _Pragma("unroll")                                                     \
        for (int fm = 0; fm < 4; ++fm) {                                      \
            FA[fm] = *(const half8*)(pA[fm] + _o);                            \
            FB[fm] = *(const half8*)(pB[fm] + _o);                            \
        }                                                                     \
    } while (0)

#define COMPUTE(FA, FB)                                                       \
    do {                                                                      \
        _Pragma("unroll")                                                     \
        for (int fn = 0; fn < 4; ++fn) {                                      \
            const float c0 = c0v[fn], s0 = s0v[fn];                           \
            const half2v c0b = __builtin_amdgcn_cvt_pkrtz(c0, c0);            \
            const half2v s0b = __builtin_amdgcn_cvt_pkrtz(s0, s0);            \
            BF fc, fs, fns;                                                   \
            _Pragma("unroll")                                                 \
            for (int i = 0; i < 4; ++i) {                                     \
                fc.h2[i] = c0b * PC[fn][i] - s0b * PS[fn][i];                 \
                fs.h2[i] = s0b * PC[fn][i] + c0b * PS[fn][i];                 \
            }                                                                 \
            fns.u.x = fs.u.x ^ 0x80008000u;                                   \
            fns.u.y = fs.u.y ^ 0x80008000u;                                   \
            fns.u.z = fs.u.z ^ 0x80008000u;                                   \
            fns.u.w = fs.u.w ^ 0x80008000u;                                   \
            _Pragma("unroll")                                                 \
            for (int fm = 0; fm < 4; ++fm) {                                  \
                accRe[fm][fn] = __builtin_amdgcn_mfma_f32_16x16x32_f16(FA[fm], fc.v,  accRe[fm][fn], 0, 0, 0); \
                accRe[fm][fn] = __builtin_amdgcn_mfma_f32_16x16x32_f16(FB[fm], fs.v,  accRe[fm][fn], 0, 0, 0); \
                accIm[fm][fn] = __builtin_amdgcn_mfma_f32_16x16x32_f16(FB[fm], fc.v,  accIm[fm][fn], 0, 0, 0); \
                accIm[fm][fn] = __builtin_amdgcn_mfma_f32_16x16x32_f16(FA[fm], fns.v, accIm[fm][fn], 0, 0, 0); \
            }                                                                 \
            c0v[fn] = __builtin_fmaf(c0, C32[fn], -(s0 * S32[fn]));           \
            s0v[fn] = __builtin_fmaf(s0, C32[fn],  (c0 * S32[fn]));           \
        }                                                                     \
    } while (0)

    // ---- software-pipelined K-loop: ping-pong register prefetch ----
    LOADF(A0, B0, 0);
    for (int t = 0; t < N_SZ / KT; t += 2) {
        LOADF(A1, B1, t + 1);          // prefetch odd step (hides under even MFMAs)
        COMPUTE(A0, B0);
        if (t + 2 < N_SZ / KT) LOADF(A0, B0, t + 2);   // prefetch next even step
        COMPUTE(A1, B1);
    }
#undef LOADF
#undef COMPUTE

    // ---- epilogue: out = (re^2 + im^2)/N ----
    // D frag layout (measured m89): col = lane&15, row = (lane>>4)*4 + reg
    const float inv = 1.0f / (float)N_SZ;
    const int orow0 = b0 + wr + ((lane >> 4) << 2);
    const int ocol0 = m0 + wc + (lane & 15);
#pragma unroll
    for (int fm = 0; fm < 4; ++fm)
#pragma unroll
        for (int fn = 0; fn < 4; ++fn) {
            const f32x4 r = accRe[fm][fn];
            const f32x4 im = accIm[fm][fn];
            const int col = ocol0 + fn * 16;
#pragma unroll
            for (int j = 0; j < 4; ++j) {
                const int row = orow0 + fm * 16 + j;
                out[(size_t)row * M_SZ + col] = (r[j] * r[j] + im[j] * im[j]) * inv;
            }
        }
}

extern "C" void kernel_launch(void* const* d_in, const int* in_sizes, int n_in,
                              void* d_out, int out_size, void* d_ws, size_t ws_size,
                              hipStream_t stream) {
    const float* x     = (const float*)d_in[0];
    const float* xgrid = (const float*)d_in[1];
    float* out = (float*)d_out;
    unsigned char* ws = (unsigned char*)d_ws;
    // pre-convert x -> f16 fragment-tiled (2 MB in d_ws)
    cvt_kernel<<<512, 256, 0, stream>>>(x, ws);
    dim3 grid(B_SZ / BT * (M_SZ / MT));   // 4 * 128 = 512 blocks
    dim3 block(256);
    periodogram_kernel<<<grid, block, 0, stream>>>(ws, xgrid, out);
}

// Round 16
// 66.734 us; speedup vs baseline: 1.1341x; 1.1341x over previous
//
#include <hip/hip_runtime.h>

// Periodogram: out[b,m] = (re^2 + im^2)/N,  re = aC + bS, im = bC - aS
// r16: barrier-free streaming (r14) + wave-private LDS double-buffer filled by
// async global_load_lds DMA (zero VGPR cost prefetch). ds_read b128 lane-linear,
// conflict-free. No __syncthreads in the K-loop; buffers are per-wave.

typedef __fp16 half8  __attribute__((ext_vector_type(8)));
typedef __fp16 half2v __attribute__((ext_vector_type(2)));
typedef float  f32x4  __attribute__((ext_vector_type(4)));

#define B_SZ 512
#define N_SZ 1024
#define M_SZ 16384
#define BT 128
#define MT 128
#define KT 32
#define NT (N_SZ / KT)
#define WS_ARR 1048576   // bytes per converted array (512*1024*2)

union U4 { half2v h2[4]; uint4 u; };
union BF { half2v h2[4]; half8 v; uint4 u; };

__device__ __forceinline__ void gld16(const void* g, void* l) {
    __builtin_amdgcn_global_load_lds((__attribute__((address_space(1))) void*)g,
                                     (__attribute__((address_space(3))) void*)l,
                                     16, 0, 0);
}

// ---- pre-kernel: x (f32) -> d_ws (f16, fragment-tiled) ----
__global__ __launch_bounds__(256)
void cvt_kernel(const float* __restrict__ x, unsigned char* __restrict__ ws) {
    const int id  = (int)blockIdx.x * 256 + (int)threadIdx.x;  // 0..131071
    const int arr = id >> 16;            // 0=a, 1=b
    const int rem = id & 65535;
    const int rb  = rem >> 11;           // row block 0..31
    const int kc  = (rem >> 6) & 31;     // k chunk 0..31
    const int l6  = rem & 63;
    const int r16 = l6 >> 2;             // row in block
    const int g   = l6 & 3;              // k sub-group
    const float* src = x + (size_t)(rb * 16 + r16) * 2048 + arr * 1024 + kc * 32 + g * 8;
    const float4 v0 = *(const float4*)src;
    const float4 v1 = *(const float4*)(src + 4);
    U4 u;
    u.h2[0] = __builtin_amdgcn_cvt_pkrtz(v0.x, v0.y);
    u.h2[1] = __builtin_amdgcn_cvt_pkrtz(v0.z, v0.w);
    u.h2[2] = __builtin_amdgcn_cvt_pkrtz(v1.x, v1.y);
    u.h2[3] = __builtin_amdgcn_cvt_pkrtz(v1.z, v1.w);
    *(uint4*)(ws + (size_t)arr * WS_ARR + (size_t)(rb * 32 + kc) * 1024 + (g * 16 + r16) * 16) = u.u;
}

__global__ __launch_bounds__(256, 2)
void periodogram_kernel(const unsigned char* __restrict__ ws,
                        const float* __restrict__ xgrid,
                        float* __restrict__ out) {
    // 4 waves x 2 buffers x 8 KB (A frags 0..4K, B frags 4K..8K), wave-private
    __shared__ __align__(16) unsigned char smem[65536];
    const int tid  = (int)threadIdx.x;
    const int lane = tid & 63;
    const int w    = tid >> 6;
    const int bid  = (int)blockIdx.x;
    const int b0 = (bid & 3) * BT;
    const int m0 = (bid >> 2) * MT;

    const int wr = (w >> 1) * 64;   // wave row offset in tile
    const int wc = (w & 1) * 64;    // wave col offset in tile

    unsigned char* lb = smem + (unsigned)(w * 16384);

    // ---- fragment source pointers (lane-linear within 1KB tiles) ----
    const unsigned char* pA[4];
    const unsigned char* pB[4];
#pragma unroll
    for (int fm = 0; fm < 4; ++fm) {
        const int rb = ((b0 + wr) >> 4) + fm;
        pA[fm] = ws + (size_t)(rb * 32) * 1024 + (size_t)(lane * 16);
        pB[fm] = pA[fm] + WS_ARR;
    }

    // ---- per-lane trig state for the B operand (register-resident) ----
    half2v PC[4][4], PS[4][4];
    float c0v[4], s0v[4], C32[4], S32[4];
    const float g8f = (float)((lane >> 4) << 3);
#pragma unroll
    for (int fn = 0; fn < 4; ++fn) {
        const float xg = xgrid[m0 + wc + fn * 16 + (lane & 15)];
        float Cj[8], Sj[8];
        Cj[0] = 1.0f; Sj[0] = 0.0f;
#pragma unroll
        for (int j = 1; j < 8; ++j) {
            float p = xg * (float)j; p -= floorf(p);
            Cj[j] = __builtin_amdgcn_cosf(p);   // cos(2*pi*p)
            Sj[j] = __builtin_amdgcn_sinf(p);
        }
#pragma unroll
        for (int i = 0; i < 4; ++i) {
            PC[fn][i] = __builtin_amdgcn_cvt_pkrtz(Cj[2 * i], Cj[2 * i + 1]);
            PS[fn][i] = __builtin_amdgcn_cvt_pkrtz(Sj[2 * i], Sj[2 * i + 1]);
        }
        float p32 = xg * 32.0f; p32 -= floorf(p32);      // exact product
        C32[fn] = __builtin_amdgcn_cosf(p32);
        S32[fn] = __builtin_amdgcn_sinf(p32);
        float pb = xg * g8f; pb -= floorf(pb);
        c0v[fn] = __builtin_amdgcn_cosf(pb);
        s0v[fn] = __builtin_amdgcn_sinf(pb);
    }

    f32x4 accRe[4][4], accIm[4][4];
#pragma unroll
    for (int i = 0; i < 4; ++i)
#pragma unroll
        for (int j = 0; j < 4; ++j) { accRe[i][j] = (f32x4)0.0f; accIm[i][j] = (f32x4)0.0f; }

    // ---- prologue: DMA-stage t=0 into buffer 0 (wave-private) ----
#pragma unroll
    for (int fm = 0; fm < 4; ++fm) {
        gld16(pA[fm], lb + (unsigned)(fm * 1024));
        gld16(pB[fm], lb + (unsigned)(4096 + fm * 1024));
    }

    for (int t = 0; t < NT; ++t) {
        const unsigned cb = (unsigned)(t & 1) * 8192u;
        // current buffer's DMA complete (only this wave's loads are counted)
        asm volatile("s_waitcnt vmcnt(0)" ::: "memory");
        // ---- ds_read fragments (lane-linear, conflict-free b128) ----
        half8 fa[4], fb[4];
#pragma unroll
        for (int fm = 0; fm < 4; ++fm) {
            fa[fm] = *(const half8*)(lb + cb + (unsigned)(fm * 1024) + (unsigned)(lane * 16));
            fb[fm] = *(const half8*)(lb + cb + (unsigned)(4096 + fm * 1024) + (unsigned)(lane * 16));
        }
        // ---- issue next step's DMA into the other buffer ----
        if (t < NT - 1) {
            const unsigned nb = cb ^ 8192u;
            const unsigned off = (unsigned)((t + 1) * 1024);
#pragma unroll
            for (int fm = 0; fm < 4; ++fm) {
                gld16(pA[fm] + off, lb + nb + (unsigned)(fm * 1024));
                gld16(pB[fm] + off, lb + nb + (unsigned)(4096 + fm * 1024));
            }
        }
        // ---- compute: trig in registers + 64 MFMA ----
#pragma unroll
        for (int fn = 0; fn < 4; ++fn) {
            const float c0 = c0v[fn], s0 = s0v[fn];
            const half2v c0b = __builtin_amdgcn_cvt_pkrtz(c0, c0);
            const half2v s0b = __builtin_amdgcn_cvt_pkrtz(s0, s0);
            BF fc, fs, fns;
#pragma unroll
            for (int i = 0; i < 4; ++i) {
                fc.h2[i] = c0b * PC[fn][i] - s0b * PS[fn][i];   // pk_mul+pk_fma
                fs.h2[i] = s0b * PC[fn][i] + c0b * PS[fn][i];
            }
            fns.u.x = fs.u.x ^ 0x80008000u;
            fns.u.y = fs.u.y ^ 0x80008000u;
            fns.u.z = fs.u.z ^ 0x80008000u;
            fns.u.w = fs.u.w ^ 0x80008000u;
#pragma unroll
            for (int fm = 0; fm < 4; ++fm) {
                accRe[fm][fn] = __builtin_amdgcn_mfma_f32_16x16x32_f16(fa[fm], fc.v,  accRe[fm][fn], 0, 0, 0);
                accRe[fm][fn] = __builtin_amdgcn_mfma_f32_16x16x32_f16(fb[fm], fs.v,  accRe[fm][fn], 0, 0, 0);
                accIm[fm][fn] = __builtin_amdgcn_mfma_f32_16x16x32_f16(fb[fm], fc.v,  accIm[fm][fn], 0, 0, 0);
                accIm[fm][fn] = __builtin_amdgcn_mfma_f32_16x16x32_f16(fa[fm], fns.v, accIm[fm][fn], 0, 0, 0);
            }
            // advance base state by Delta-k = 32 (f32, depth-2)
            c0v[fn] = __builtin_fmaf(c0, C32[fn], -(s0 * S32[fn]));
            s0v[fn] = __builtin_fmaf(s0, C32[fn],  (c0 * S32[fn]));
        }
    }

    // ---- epilogue: out = (re^2 + im^2)/N ----
    // D frag layout (measured m89): col = lane&15, row = (lane>>4)*4 + reg
    const float inv = 1.0f / (float)N_SZ;
    const int orow0 = b0 + wr + ((lane >> 4) << 2);
    const int ocol0 = m0 + wc + (lane & 15);
#pragma unroll
    for (int fm = 0; fm < 4; ++fm)
#pragma unroll
        for (int fn = 0; fn < 4; ++fn) {
            const f32x4 r = accRe[fm][fn];
            const f32x4 im = accIm[fm][fn];
            const int col = ocol0 + fn * 16;
#pragma unroll
            for (int j = 0; j < 4; ++j) {
                const int row = orow0 + fm * 16 + j;
                out[(size_t)row * M_SZ + col] = (r[j] * r[j] + im[j] * im[j]) * inv;
            }
        }
}

extern "C" void kernel_launch(void* const* d_in, const int* in_sizes, int n_in,
                              void* d_out, int out_size, void* d_ws, size_t ws_size,
                              hipStream_t stream) {
    const float* x     = (const float*)d_in[0];
    const float* xgrid = (const float*)d_in[1];
    float* out = (float*)d_out;
    unsigned char* ws = (unsigned char*)d_ws;
    // pre-convert x -> f16 fragment-tiled (2 MB in d_ws)
    cvt_kernel<<<512, 256, 0, stream>>>(x, ws);
    dim3 grid(B_SZ / BT * (M_SZ / MT));   // 4 * 128 = 512 blocks
    dim3 block(256);
    periodogram_kernel<<<grid, block, 0, stream>>>(ws, xgrid, out);
}